// Round 11
// baseline (35.956 us; speedup 1.0000x reference)
//
#include <hip/hip_runtime.h>
#include <cfloat>

#define NS 7
#define NC 256
#define NH 64
#define NW 64
#define NR 128

#define RFL(x) __builtin_amdgcn_readfirstlane(x)

// Kernel 1: CHW -> HWC transpose into d_ws (round-6 structure: pad-65 LDS is
// conflict-free both phases, loads/stores coalesced 256B). Grid 256, ~1.5us.
__global__ __launch_bounds__(256) void transpose_chw_hwc(
    const float* __restrict__ f, float* __restrict__ ft)
{
    __shared__ float tile[64][65];   // [w][c]
    const int tid = threadIdx.x;
    const int h   = blockIdx.x >> 2;
    const int c0  = (blockIdx.x & 3) * 64;

    #pragma unroll
    for (int k = 0; k < 16; ++k) {
        int q = tid + k * 256;
        int c = q >> 6;          // 0..63
        int w = q & 63;          // lane-consecutive -> coalesced reads
        tile[w][c] = f[(size_t)(c0 + c) * (NH * NW) + h * NW + w];
    }
    __syncthreads();
    #pragma unroll
    for (int k = 0; k < 16; ++k) {
        int q = tid + k * 256;
        int w = q >> 6;
        int c = q & 63;          // lane-consecutive -> coalesced writes
        ft[(size_t)h * (NW * NC) + w * NC + c0 + c] = tile[w][c];
    }
}

// Kernel 2: wave = (r, bin, c-half). lane = 2 channels (float2, 512B/load).
// All bounds scalar (RFL'd task id -> SALU), loads saddr-form (0 VALU/load),
// window = fully-unrolled clamped-dup volleys, one waitcnt per volley.
// 12544 wave-tasks, 3136 blocks = 3x oversubscribed -> balanced.
__global__ __launch_bounds__(256, 4) void roi_pool_hwc(
    const float* __restrict__ ft, const int* __restrict__ rois,
    float* __restrict__ out)
{
    const int lane = threadIdx.x & 63;
    const int Wv   = RFL(blockIdx.x * 4 + (threadIdx.x >> 6));

    const int cg  = Wv & 1;          // c-half: 0 -> c 0..127, 1 -> c 128..255
    const int t   = Wv >> 1;         // r*49 + bin
    const int bin = t % (NS * NS);
    const int r   = t / (NS * NS);
    const int i   = bin / NS;
    const int j   = bin - i * NS;

    const int x1 = RFL(rois[4 * r + 0]);   // H range
    const int y1 = RFL(rois[4 * r + 1]);   // W range
    const int x2 = RFL(rois[4 * r + 2]);
    const int y2 = RFL(rois[4 * r + 3]);
    const int Lh = x2 - x1 + 1;
    const int Lw = y2 - y1 + 1;

    const int h0 = x1 + (i * Lh) / NS;
    const int h1 = x1 + ((i + 1) * Lh + NS - 1) / NS;
    const int w0 = y1 + (j * Lw) / NS;
    const int w1 = y1 + ((j + 1) * Lw + NS - 1) / NS;
    const int sph = h1 - h0;         // in {K, K+1}, K = ceil(Lh/7)
    const int spw = w1 - w0;

    // per-lane base: 2 consecutive channels; all (h,w) offsets are scalar
    const float* base = ft + cg * 128 + lane * 2;

    float2 acc = make_float2(-FLT_MAX, -FLT_MAX);

    if (sph <= 2 && spw <= 2) {
        // 2x2 clamped volley: 4 independent loads, one waitcnt (~45% of bins)
        const int hB = min(h0 + 1, h1 - 1);
        const int wB = min(w0 + 1, w1 - 1);
        float2 v0 = *(const float2*)(base + (size_t)(h0 * NW + w0) * NC);
        float2 v1 = *(const float2*)(base + (size_t)(h0 * NW + wB) * NC);
        float2 v2 = *(const float2*)(base + (size_t)(hB * NW + w0) * NC);
        float2 v3 = *(const float2*)(base + (size_t)(hB * NW + wB) * NC);
        acc.x = fmaxf(fmaxf(v0.x, v1.x), fmaxf(v2.x, v3.x));
        acc.y = fmaxf(fmaxf(v0.y, v1.y), fmaxf(v2.y, v3.y));
    } else {
        // 4x4 clamped-dup volleys over super-tiles (scalar loops, uniform)
        for (int a = 0; a < sph; a += 4) {
            for (int b = 0; b < spw; b += 4) {
                #pragma unroll
                for (int dh = 0; dh < 4; ++dh) {
                    const int h = min(h0 + a + dh, h1 - 1);
                    #pragma unroll
                    for (int dw = 0; dw < 4; ++dw) {
                        const int w = min(w0 + b + dw, w1 - 1);
                        float2 v = *(const float2*)(base + (size_t)(h * NW + w) * NC);
                        acc.x = fmaxf(acc.x, v.x);
                        acc.y = fmaxf(acc.y, v.y);
                    }
                }
            }
        }
    }

    // out[r][c][bin], c = cg*128 + lane*2 (+1): stride 49 floats between the two
    const int c = cg * 128 + lane * 2;
    float* op = out + ((size_t)r * NC + c) * (NS * NS) + bin;
    op[0]          = acc.x;
    op[NS * NS]    = acc.y;
}

extern "C" void kernel_launch(void* const* d_in, const int* in_sizes, int n_in,
                              void* d_out, int out_size, void* d_ws, size_t ws_size,
                              hipStream_t stream)
{
    const float* feature_map = (const float*)d_in[0];
    const int*   rois        = (const int*)d_in[1];
    float*       out         = (float*)d_out;
    float*       ft          = (float*)d_ws;   // 4 MB HWC scratch

    transpose_chw_hwc<<<NH * 4, 256, 0, stream>>>(feature_map, ft);

    const int nwaves = NR * NS * NS * 2;       // 12544
    roi_pool_hwc<<<nwaves / 4, 256, 0, stream>>>(ft, rois, out);
}